// Round 15
// baseline (145.930 us; speedup 1.0000x reference)
//
#include <hip/hip_runtime.h>

// PartialGConv: partial temporal conv (TK=9, pad 4) + mask-ratio + graph einsum.
// FUSED kernel, r15: ZERO-BARRIER K-loop. Each wave owns a private LDS A
// double-buffer (48 rows x 32k x 2 bufs = 6KB/wave) staged via its own
// global_load_lds and ordered by its own per-wave vmcnt — no s_barrier for the
// whole 18-step loop (B window is read-only after one prologue barrier).
// Geometry = r12 (1024 thr, 16 waves 4Mx4N, BM=192, BN=208(200 useful), K=576).
// LDS 150.5KB -> 1 block/CU = 4 waves/SIMD (same occupancy as r13/14: isolates
// the barrier variable). Epilogue = r12 (MFMA contraction, Pl stride 344).
//
// ws layout (bytes):
//   xmr  u16[32][6656][64]  @0          x*mask bf16 row-major, padded rows
//   wb   u16[192][576]      @27,262,976 weights bf16, k=dt*64+cin, 16B-slot swizzled
//   msum f32[32][6400]      @27,484,160 sum_cin mask
//   s    f32[32][6400]      @28,303,360 576/(upd+eps)*uc^2
//   mr   f32[32][6400]      @29,122,560 mask_ratio
//   mb   f32[32][6400]      @29,941,760 m_bool
//   Bc   f32[32][3][256][25]@30,760,960 sum_v uc*A[k,v,w]

typedef unsigned short u16;
typedef unsigned int u32;
typedef short short8 __attribute__((ext_vector_type(8)));
typedef float f32x4 __attribute__((ext_vector_type(4)));

#define TV 6400
#define KC 192
#define KDIM 576
#define NPADT 6656          // 100 front pad + 6400 + 156 back pad
#define Y_SIZE 13107200
#define MB_OFF 13109075     // Y_SIZE + 1875

#define OFF_WB   27262976
#define OFF_MSUM 27484160
#define OFF_S    28303360
#define OFF_MR   29122560
#define OFF_MB   29941760
#define OFF_BC   30760960

// LDS map (150,528 B total). K-loop: xwin [0,52224) = 408 rows x 128B;
// per-wave A @52224 + wid*6144 (2 bufs x 3072B each).
// Epilogue aliases: Pl u16[64][344] @0 (44,032); Ys f32[32][201] @0;
// misc @52224: Ab 6144 | Bcs 2400 | mrs 800 | bias 768 | ss 800 | mbs 800.
#define L_A     52224
#define L_AB    52224
#define L_BCS   58368
#define L_MRS   60768
#define L_BIAS  61568
#define L_SS    62336
#define L_MBS   63136

#define VMCNT(N) asm volatile("s_waitcnt vmcnt(" #N ")" ::: "memory")

__device__ __forceinline__ u16 f2bf(float f) {
  u32 u = __builtin_bit_cast(u32, f);
  u = (u + 0x7FFFu + ((u >> 16) & 1u)) >> 16;   // RTNE
  return (u16)u;
}
__device__ __forceinline__ float bf2f(u16 h) {
  return __builtin_bit_cast(float, (u32)h << 16);
}
__device__ __forceinline__ void gload_lds16(const u16* g, u16* l) {
  __builtin_amdgcn_global_load_lds(
      (const __attribute__((address_space(1))) u32*)(const void*)g,
      (__attribute__((address_space(3))) u32*)(void*)l, 16, 0, 0);
}

// ---- zero the temporal pad rows of xmr --------------------------------------
__global__ void k_pad(u16* __restrict__ xmr) {
  int i = blockIdx.x * 256 + threadIdx.x;       // 65536 uint4
  if (i >= 65536) return;
  int n = i >> 11, r = i & 2047;                // 256 pad rows x 8 uint4
  int row = r >> 3, c = r & 7;
  int tvrow = (row < 100) ? row : (6400 + row); // front 0..99 / back 6500..6655
  uint4 z; z.x = z.y = z.z = z.w = 0u;
  *(uint4*)(xmr + ((size_t)n * NPADT + tvrow) * 64 + c * 8) = z;
}

// ---- xmr = bf16(x*mask) row-major [tvp][64] + msum = sum_cin mask ------------
__global__ void k_xmT(const float* __restrict__ x, const float* __restrict__ mask,
                      u16* __restrict__ xmr, float* __restrict__ msum) {
  const int tvb = blockIdx.x, n = blockIdx.y;   // grid (100, 32), block 256
  const int tvl = threadIdx.x & 63, q = threadIdx.x >> 6;  // 4 quads of 16 cin
  const int tv = tvb * 64 + tvl;
  const float* xp = x + ((size_t)n * 64 + q * 16) * TV + tv;
  const float* mp = mask + ((size_t)n * 64 + q * 16) * TV + tv;
  u16 vals[16];
  float msacc = 0.f;
#pragma unroll
  for (int j = 0; j < 16; ++j) {                // coalesced: lanes = consecutive tv
    float xv = xp[(size_t)j * TV];
    float mv = mp[(size_t)j * TV];
    msacc += mv;
    vals[j] = f2bf(xv * mv);
  }
  uint4 lo, hi;
  lo.x = vals[0] | ((u32)vals[1] << 16);  lo.y = vals[2] | ((u32)vals[3] << 16);
  lo.z = vals[4] | ((u32)vals[5] << 16);  lo.w = vals[6] | ((u32)vals[7] << 16);
  hi.x = vals[8] | ((u32)vals[9] << 16);  hi.y = vals[10] | ((u32)vals[11] << 16);
  hi.z = vals[12] | ((u32)vals[13] << 16); hi.w = vals[14] | ((u32)vals[15] << 16);
  u16* dst = xmr + ((size_t)n * NPADT + 100 + tv) * 64 + q * 16;
  *(uint4*)dst = lo;
  *(uint4*)(dst + 8) = hi;
  __shared__ float red[4][64];
  red[q][tvl] = msacc;
  __syncthreads();
  if (q == 0) msum[n * TV + tv] = red[0][tvl] + red[1][tvl] + red[2][tvl] + red[3][tvl];
}

// ---- wb[kc][k=dt*64+cin], bf16, 16B-slot XOR pre-swizzle (by (kc>>1)&3) -----
__global__ void k_w(const float* __restrict__ weight, u16* __restrict__ wb) {
  int i = blockIdx.x * 256 + threadIdx.x;      // 110592
  if (i >= 110592) return;
  int kc = i / KDIM, k = i % KDIM;
  int cin = k & 63, dt = k >> 6;
  float v = weight[(kc * 64 + cin) * 9 + dt];
  int phys = (k & ~31) | ((((k >> 3) & 3) ^ ((kc >> 1) & 3)) << 3) | (k & 7);
  wb[kc * KDIM + phys] = f2bf(v);
}

// ---- per (n,t): upd -> s, mask_ratio, m_bool, Bc ----------------------------
__global__ void k_prep(const float* __restrict__ msum, const float* __restrict__ A_g,
                       float* __restrict__ s_ws, float* __restrict__ mr_ws,
                       float* __restrict__ mb_ws, float* __restrict__ Bc_ws) {
  int b = blockIdx.x;                          // 8192 = n*256 + t
  int n = b >> 8, t = b & 255;
  int tid = threadIdx.x;                       // 64
  __shared__ float uc[25];
  if (tid < 25) {
    float upd = 0.f;
    for (int dt = 0; dt < 9; ++dt) {
      int tt = t + dt - 4;
      if (tt >= 0 && tt < 256) upd += msum[n * TV + tt * 25 + tid];
    }
    float u_c = fminf(fmaxf(upd, 0.f), 1.f);
    float ratio = 576.f / (upd + 1e-8f);
    s_ws[n * TV + t * 25 + tid] = ratio * u_c * u_c;  // coeff of raw in out
    uc[tid] = u_c;
  }
  __syncthreads();
  if (tid < 25) {
    int w = tid;
    float M = 0.f;
    for (int k = 0; k < 3; ++k) {
      float acc = 0.f;
      for (int v = 0; v < 25; ++v) acc += uc[v] * A_g[(k * 25 + v) * 25 + w];
      Bc_ws[((size_t)(n * 3 + k) * 256 + t) * 25 + w] = acc;
      M += acc;
    }
    float mbv = (M != 0.f) ? 1.f : 0.f;
    mr_ws[n * TV + t * 25 + w] = mbv / (M + 1e-8f);
    mb_ws[n * TV + t * 25 + w] = mbv;
  }
}

// ---- FUSED: implicit-GEMM + MFMA (k,v)-contraction + coalesced epilogue -----
// Block (tg, n): 1024 threads, 16 waves = 4(M) x 4(N). Wave cols: wn<3 -> 4
// frags (64 cols), wn=3 -> 1 frag (cols 192-207; 200-207 dead, guarded).
// K-loop: zero barriers — each wave stages its own A rows (wm*48..+47) into
// a private LDS double-buffer, ordered by its own counted vmcnt.
__global__ __launch_bounds__(1024, 4) void k_fused(
    const u16* __restrict__ xmr, const u16* __restrict__ wb,
    const float* __restrict__ s_g, const float* __restrict__ A_g,
    const float* __restrict__ Bc_g, const float* __restrict__ mr_g,
    const float* __restrict__ mb_g, const float* __restrict__ bias_g,
    float* __restrict__ out) {
  __shared__ __align__(16) char ring[150528];

  const int tid = threadIdx.x;
  const int tg = blockIdx.x;                  // 0..31 (8-t group)
  const int n = blockIdx.y;                   // 0..31
  const int tv0 = tg * 200;
  const int lane = tid & 63, wid = tid >> 6;
  const int wm = wid >> 2, wn = wid & 3;
  const int lrow = lane & 15, lgrp = lane >> 4;
  const int nf = (wn == 3) ? 1 : 4, colb = wn * 64;

  const u16* xmn = xmr + (size_t)n * NPADT * 64;
  u16* xwin = (u16*)(ring);
  u16* awave = (u16*)(ring + L_A) + wid * 3072;   // private: 2 bufs x 1536 u16

  f32x4 acc[3][4] = {};

  // Per-wave A staging: 3 x gload_lds16 covering rows wm*48..wm*48+47, one k-step.
  auto stageA = [&](int buf, int ks) {
    u16* dst = awave + buf * 1536;
#pragma unroll
    for (int t = 0; t < 3; ++t) {
      const u16* src = wb + (size_t)(wm * 48 + t * 16 + (lane >> 2)) * KDIM + ks * 32 + (lane & 3) * 8;
      gload_lds16(src, dst + t * 512);
    }
  };

  // ---- prologue: stage B window (51 loads over 16 waves) + own A(0) ---------
  {
    // LDS[row][slot] = global[row][slot ^ (row&7)] in window coords; tv0%8==0.
    const int srow_g = lane >> 3, sl = (lane & 7) ^ (lane >> 3);  // per-lane
    for (int t = wid; t < 51; t += 16) {
      const u16* src = xmn + ((size_t)(tv0 + t * 8 + srow_g) * 64 + sl * 8);
      gload_lds16(src, xwin + t * 512);
    }
    stageA(0, 0);
  }
  VMCNT(0);
  __builtin_amdgcn_s_barrier();      // xwin (+ everyone's A0) visible
  asm volatile("" ::: "memory");

  // ---- K-loop: 18 steps, ZERO barriers --------------------------------------
  // Per-wave invariant: at top of step ks, buf[ks&1] holds this wave's A(ks)
  // (waited via this wave's own VMCNT last step). Writing buf[(ks+1)&1] is
  // safe: this wave's step-(ks-1) ds_reads of that buffer retired before its
  // step-(ks-1) MFMAs (lgkmcnt ordering), which precede this stage in program
  // order. xwin is read-only. No cross-wave hazards exist.
  for (int ks = 0; ks < 18; ++ks) {
    if (ks < 17) {
      stageA((ks + 1) & 1, ks + 1);
      VMCNT(3);                      // wait own A(ks) loads; A(ks+1)'s 3 in flight
    } else {
      VMCNT(0);
    }

    const u16* abuf = awave + (ks & 1) * 1536;
    short8 af[3];
#pragma unroll
    for (int m = 0; m < 3; ++m) {
      int arow = wm * 48 + m * 16 + lrow;
      af[m] = *(const short8*)&abuf[(m * 16 + lrow) * 32 + ((lgrp ^ ((arow >> 1) & 3)) << 3)];
    }
    const int dt = ks >> 1;
    const int rbase = 100 + (dt - 4) * 25 + colb + lrow;   // window row for ct=0
    const int slb = (ks & 1) * 4 + lgrp;                   // logical 16B slot
#pragma unroll
    for (int ct = 0; ct < 4; ++ct) {
      if (ct < nf) {
        int srow = rbase + ct * 16;
        short8 bfr = *(const short8*)&xwin[srow * 64 + ((slb ^ (srow & 7)) << 3)];
#pragma unroll
        for (int m = 0; m < 3; ++m)
          acc[m][ct] = __builtin_amdgcn_mfma_f32_16x16x32_bf16(af[m], bfr, acc[m][ct], 0, 0, 0);
      }
    }
  }

  // ---- epilogue setup: zero Pl, stage Ab/Bcs/mrs/bias/ss/mbs ---------------
  __syncthreads();                     // all waves done with xwin/awave; alias OK
  u16*   Plu   = (u16*)ring;           // [64][344]: tcol = t*40+v, pads zero
  u16*   Abu   = (u16*)(ring + L_AB);  // [3k][2nt][16w][32v] bf16 B-frag layout
  float* Bcsf  = (float*)(ring + L_BCS);
  float* mrsf  = (float*)(ring + L_MRS);
  float* biasf = (float*)(ring + L_BIAS);
  float* ssf   = (float*)(ring + L_SS);
  float* mbsf  = (float*)(ring + L_MBS);
  {
    uint4 z; z.x = z.y = z.z = z.w = 0u;
    for (int i = tid; i < 2752; i += 1024) ((uint4*)ring)[i] = z;  // zero Pl 44KB
  }
  for (int i = tid; i < 3072; i += 1024) {
    int kk = i >> 10, r = i & 1023;
    int nt = r >> 9, rr = r & 511, wl = rr >> 5, v = rr & 31;
    int w = nt * 16 + wl;
    float val = (v < 25 && w < 25) ? A_g[(kk * 25 + v) * 25 + w] : 0.f;
    Abu[i] = f2bf(val);
  }
  if (tid < 600) {
    int k = tid / 200, t = (tid % 200) / 25, w = tid % 25;
    Bcsf[tid] = Bc_g[((size_t)(n * 3 + k) * 256 + tg * 8 + t) * 25 + w];
  }
  if (tid < 200) {
    mrsf[tid] = mr_g[n * TV + tv0 + tid];
    ssf[tid]  = s_g[n * TV + tv0 + tid];
    mbsf[tid] = mb_g[n * TV + tv0 + tid];
  }
  if (tid >= 512 && tid < 704) biasf[tid - 512] = bias_g[tid - 512];
  __syncthreads();

  // ---- MFMA contraction: y(ct,w) = sum_v P(ct,v) * A(v,w), per-k -----------
  f32x4 yacc[2][2] = {};
  for (int k = 0; k < 3; ++k) {
    // stage Pl_k = bf16(acc * s) for rows of this k
#pragma unroll
    for (int m = 0; m < 3; ++m) {
      int R = wm * 48 + m * 16 + lgrp * 4;
      if ((R >> 6) == k) {
        int cb = R & 63;
#pragma unroll
        for (int ct = 0; ct < 4; ++ct) {
          if (ct < nf) {
            int col = colb + ct * 16 + lrow;
            if (col < 200) {
              int t = col / 25, v = col - t * 25;
              float sv = ssf[col];
              int tc = t * 40 + v;
#pragma unroll
              for (int r = 0; r < 4; ++r)
                Plu[(cb + r) * 344 + tc] = f2bf(acc[m][ct][r] * sv);
            }
          }
        }
      }
    }
    __syncthreads();
    // contraction MFMAs: wave owns M-tiles {wid*2, wid*2+1}
    short8 pb[2];
#pragma unroll
    for (int nt = 0; nt < 2; ++nt)
      pb[nt] = *(const short8*)&Abu[((k * 2 + nt) * 16 + lrow) * 32 + lgrp * 8];
#pragma unroll
    for (int mi = 0; mi < 2; ++mi) {
      int mt = wid * 2 + mi;
      const short8 pa = *(const short8*)
          &Plu[(mt * 2 + (lrow >> 3)) * 344 + (lrow & 7) * 40 + lgrp * 8];
#pragma unroll
      for (int nt = 0; nt < 2; ++nt)
        yacc[mi][nt] = __builtin_amdgcn_mfma_f32_16x16x32_bf16(pa, pb[nt], yacc[mi][nt], 0, 0, 0);
    }
    __syncthreads();                   // before next k overwrites Pl
  }

  // ---- finalize + transposed coalesced y writes ----------------------------
  // yacc[mi][nt][r]: row ct = (wid*2+mi)*16 + lgrp*4 + r, col w = nt*16 + lrow
  float (*Ysf)[201] = (float(*)[201])ring;     // aliases Pl, barrier-separated
  const size_t base_n = (size_t)(n * 64) * 6400 + tv0;
#pragma unroll
  for (int half = 0; half < 2; ++half) {
    __syncthreads();
    if ((wid >> 3) == half) {
#pragma unroll
      for (int mi = 0; mi < 2; ++mi)
#pragma unroll
        for (int nt = 0; nt < 2; ++nt) {
          int w = nt * 16 + lrow;
          if (w < 25) {
#pragma unroll
            for (int r = 0; r < 4; ++r) {
              int ct = (wid * 2 + mi) * 16 + lgrp * 4 + r;
              int c = ct >> 3, t = ct & 7;
              float bt = biasf[c] * Bcsf[t * 25 + w] +
                         biasf[64 + c] * Bcsf[200 + t * 25 + w] +
                         biasf[128 + c] * Bcsf[400 + t * 25 + w];
              Ysf[c & 31][t * 25 + w] = (yacc[mi][nt][r] + bt) * mrsf[t * 25 + w];
            }
          }
        }
    }
    __syncthreads();
    for (int i = tid; i < 6400; i += 1024) {
      int ch = i / 200, j = i % 200;
      out[base_n + (size_t)(half * 32 + ch) * 6400 + j] = Ysf[ch][j];
    }
  }

  // m_bool: c-independent broadcast, direct coalesced stores
  for (int i = tid; i < 12800; i += 1024) {
    int cc = i / 200, j = i % 200;
    out[MB_OFF + base_n + (size_t)cc * 6400 + j] = mbsf[j];
  }
}

extern "C" void kernel_launch(void* const* d_in, const int* in_sizes, int n_in,
                              void* d_out, int out_size, void* d_ws, size_t ws_size,
                              hipStream_t stream) {
  const float* x      = (const float*)d_in[0];
  const float* A      = (const float*)d_in[1];
  const float* mask   = (const float*)d_in[2];
  const float* weight = (const float*)d_in[3];
  const float* bias   = (const float*)d_in[4];
  float* out = (float*)d_out;
  char* ws = (char*)d_ws;

  u16*   xmr   = (u16*)(ws);
  u16*   wb    = (u16*)(ws + OFF_WB);
  float* msum  = (float*)(ws + OFF_MSUM);
  float* s_ws  = (float*)(ws + OFF_S);
  float* mr_ws = (float*)(ws + OFF_MR);
  float* mb_ws = (float*)(ws + OFF_MB);
  float* Bc_ws = (float*)(ws + OFF_BC);

  k_pad<<<256, 256, 0, stream>>>(xmr);
  k_xmT<<<dim3(100, 32), 256, 0, stream>>>(x, mask, xmr, msum);
  k_w<<<432, 256, 0, stream>>>(weight, wb);
  k_prep<<<8192, 64, 0, stream>>>(msum, A, s_ws, mr_ws, mb_ws, Bc_ws);

  hipMemcpyAsync(out + Y_SIZE, A, 1875 * sizeof(float),
                 hipMemcpyDeviceToDevice, stream);

  k_fused<<<dim3(32, 32), 1024, 0, stream>>>(xmr, wb, s_ws, A, Bc_ws, mr_ws,
                                             mb_ws, bias, out);
}